// Round 2
// baseline (805.720 us; speedup 1.0000x reference)
//
#include <hip/hip_runtime.h>

#define T_STEPS 256
#define BATCH   512
#define DIN     256
#define HDIM    256

typedef unsigned int u32;
typedef _Float16 h2 __attribute__((ext_vector_type(2)));

__device__ __forceinline__ u32 pack2(float a, float b) {
    return __builtin_bit_cast(u32, __builtin_amdgcn_cvt_pkrtz(a, b));
}
__device__ __forceinline__ float dot2(u32 a, u32 b, float acc) {
    return __builtin_amdgcn_fdot2(__builtin_bit_cast(h2, a),
                                  __builtin_bit_cast(h2, b), acc, false);
}
__device__ __forceinline__ float fast_sigmoid(float x) {
    return 1.0f / (1.0f + __expf(-x));
}
__device__ __forceinline__ float fast_tanh(float x) {
    return 1.0f - 2.0f / (__expf(2.0f * x) + 1.0f);
}

// c = {c0..c7}; returns sum_q out_q * W[q] where out_0 = c1*...*c7,
// out_i = c0*...*ci (i>=1).
__device__ __forceinline__ float group_dot(const float4 cA, const float4 cB, const float* W) {
    float pr = cA.x;
    float d  = 0.0f;
    pr *= cA.y; d = fmaf(pr, W[1], d);
    pr *= cA.z; d = fmaf(pr, W[2], d);
    pr *= cA.w; d = fmaf(pr, W[3], d);
    pr *= cB.x; d = fmaf(pr, W[4], d);
    pr *= cB.y; d = fmaf(pr, W[5], d);
    pr *= cB.z; d = fmaf(pr, W[6], d);
    pr *= cB.w; d = fmaf(pr, W[7], d);
    float sf = (cA.y * cA.z) * (cA.w * cB.x);
    sf *= (cB.y * cB.z) * cB.w;
    d = fmaf(sf, W[0], d);
    return d;
}

// ---------------------------------------------------------------------------
// Kernel 1: Xproj[t*B+b][g] = x_{t,b} . Wx[:,g] + b_proj[g] + theta_gate[g&7]
// (no recurrence -> fully parallel, memory-bound)
// ---------------------------------------------------------------------------
__launch_bounds__(256, 2)
__global__ void xproj_kernel(const float* __restrict__ x,
                             const float* __restrict__ W_proj,
                             const float* __restrict__ b_proj,
                             const float* __restrict__ theta_gate,
                             float* __restrict__ xp) {
    const int tid = threadIdx.x;
    const int g = tid >> 3, j = tid & 7;
    float Wr[32];
    #pragma unroll
    for (int i = 0; i < 32; ++i)
        Wr[i] = W_proj[(j * 32 + i) * 32 + g];
    const float bias = b_proj[g] + theta_gate[g & 7];
    const size_t row0 = (size_t)blockIdx.x * 64;
    #pragma unroll 1
    for (int rr = 0; rr < 64; rr += 2) {
        const float* xr = x + (row0 + rr) * DIN + j * 32;
        float acc0 = 0.0f, acc1 = 0.0f;
        #pragma unroll
        for (int c = 0; c < 8; ++c) {
            float4 v0 = ((const float4*)xr)[c];
            float4 v1 = ((const float4*)(xr + DIN))[c];
            acc0 = fmaf(Wr[4*c+0], v0.x, acc0);
            acc0 = fmaf(Wr[4*c+1], v0.y, acc0);
            acc0 = fmaf(Wr[4*c+2], v0.z, acc0);
            acc0 = fmaf(Wr[4*c+3], v0.w, acc0);
            acc1 = fmaf(Wr[4*c+0], v1.x, acc1);
            acc1 = fmaf(Wr[4*c+1], v1.y, acc1);
            acc1 = fmaf(Wr[4*c+2], v1.z, acc1);
            acc1 = fmaf(Wr[4*c+3], v1.w, acc1);
        }
        acc0 += __shfl_xor(acc0, 1); acc0 += __shfl_xor(acc0, 2); acc0 += __shfl_xor(acc0, 4);
        acc1 += __shfl_xor(acc1, 1); acc1 += __shfl_xor(acc1, 2); acc1 += __shfl_xor(acc1, 4);
        if (j == 0) {
            xp[(row0 + rr)     * 32 + g] = acc0 + bias;
            xp[(row0 + rr + 1) * 32 + g] = acc1 + bias;
        }
    }
}

// ---------------------------------------------------------------------------
// Kernel 2: recurrent core. h-dot only (x-part precomputed), f16 LDS paths.
// ---------------------------------------------------------------------------
__launch_bounds__(256, 2)
__global__ void qlstm_main(const float* __restrict__ xp_all,
                           const float* __restrict__ W_proj,
                           const float* __restrict__ W_qproj,
                           const float* __restrict__ b_qproj,
                           const float* __restrict__ theta_attn,
                           const float* __restrict__ W_attn_proj,
                           const float* __restrict__ b_attn_proj,
                           const float* __restrict__ W_attn_back,
                           const float* __restrict__ b_attn_back,
                           float* __restrict__ out) {
    const int tid = threadIdx.x;
    const int b   = blockIdx.x;
    const int g   = tid >> 3;        // gate 0..31
    const int j   = tid & 7;         // k-chunk for gate dot
    const int q   = g & 7;           // qubit within group
    const int o   = tid >> 5;        // attn output 0..7
    const int p   = tid & 31;        // attn partial lane

    // h:  8 chunks x 20 dwords (32 f16 + pad)   -> conflict-free b128 reads
    // hm: 32 rows x 6 dwords (8 f16 + pad)      -> 2-way (free) b64 reads
    __shared__ __align__(16) u32 hS[160];
    __shared__ __align__(16) u32 hmS[192];
    __shared__ __align__(16) u32 outgS[16];   // 32 gate-products, f16-packed
    __shared__ __align__(16) float caS[8];    // attn cosines

    // ---- weight preload (f16-packed where used by dot2) ----
    u32 WhP[16];
    #pragma unroll
    for (int i = 0; i < 16; ++i)
        WhP[i] = pack2(W_proj[(DIN + j * 32 + 2*i    ) * 32 + g],
                       W_proj[(DIN + j * 32 + 2*i + 1) * 32 + g]);
    u32 WqpP[4], WapP[4];
    #pragma unroll
    for (int i = 0; i < 4; ++i) {
        WqpP[i] = pack2(W_qproj[(2*i) * HDIM + tid], W_qproj[(2*i+1) * HDIM + tid]);
        WapP[i] = pack2(W_attn_proj[(p*8 + 2*i) * 8 + o], W_attn_proj[(p*8 + 2*i + 1) * 8 + o]);
    }
    float Wab[8];
    #pragma unroll
    for (int i = 0; i < 8; ++i)
        Wab[i] = W_attn_back[i * HDIM + tid];
    const float bqp = b_qproj[tid];
    const float bap = b_attn_proj[o] + theta_attn[o];
    const float bab = b_attn_back[tid];

    if (tid < 160) hS[tid] = 0u;   // h0 = 0 (f16 zeros)
    float cx = 0.0f, hx_new = 0.0f;
    float xpc = xp_all[(size_t)b * 32 + g];
    __syncthreads();

    for (int t = 0; t < T_STEPS; ++t) {
        float xpn = 0.0f;
        if (t + 1 < T_STEPS)
            xpn = xp_all[((size_t)(t + 1) * BATCH + b) * 32 + g];

        // ---- Phase A: gate pre-activation = h . Wh + xp ----
        const u32* hp = &hS[j * 20];
        uint4 u0 = ((const uint4*)hp)[0];
        uint4 u1 = ((const uint4*)hp)[1];
        uint4 u2 = ((const uint4*)hp)[2];
        uint4 u3 = ((const uint4*)hp)[3];
        float a0 = dot2(u0.x, WhP[0], 0.0f);
        a0 = dot2(u0.y, WhP[1], a0);
        a0 = dot2(u0.z, WhP[2], a0);
        a0 = dot2(u0.w, WhP[3], a0);
        a0 = dot2(u1.x, WhP[4], a0);
        a0 = dot2(u1.y, WhP[5], a0);
        a0 = dot2(u1.z, WhP[6], a0);
        a0 = dot2(u1.w, WhP[7], a0);
        float a1 = dot2(u2.x, WhP[8], 0.0f);
        a1 = dot2(u2.y, WhP[9],  a1);
        a1 = dot2(u2.z, WhP[10], a1);
        a1 = dot2(u2.w, WhP[11], a1);
        a1 = dot2(u3.x, WhP[12], a1);
        a1 = dot2(u3.y, WhP[13], a1);
        a1 = dot2(u3.z, WhP[14], a1);
        a1 = dot2(u3.w, WhP[15], a1);
        float acc = a0 + a1;
        acc += __shfl_xor(acc, 1);
        acc += __shfl_xor(acc, 2);
        acc += __shfl_xor(acc, 4);
        float c = __cosf(acc + xpc);   // <Z> per qubit = cos(z + theta)

        // in-wave prefix products over the 8 qubits of this wave's group
        float v = (q == 0) ? 1.0f : c;          // out_0 = c1*...*c7
        v *= __shfl_xor(v, 8);
        v *= __shfl_xor(v, 16);
        v *= __shfl_xor(v, 32);
        float s = c, uu;                         // out_q = c0*...*cq
        uu = __shfl_up(s, 8);  s = (q >= 1) ? s * uu : s;
        uu = __shfl_up(s, 16); s = (q >= 2) ? s * uu : s;
        uu = __shfl_up(s, 32); s = (q >= 4) ? s * uu : s;
        float outv = (q == 0) ? v : s;
        u32 po = pack2(outv, __shfl_down(outv, 8));
        if ((tid & 15) == 0) outgS[tid >> 4] = po;
        __syncthreads();

        // ---- Phase B/C: qp dots + activations + LSTM cell (thread = h) ----
        const uint4* ogp = (const uint4*)outgS;
        uint4 og0 = ogp[0], og1 = ogp[1], og2 = ogp[2], og3 = ogp[3];
        float d0 = dot2(og0.x, WqpP[0], bqp);
        d0 = dot2(og0.y, WqpP[1], d0);
        d0 = dot2(og0.z, WqpP[2], d0);
        d0 = dot2(og0.w, WqpP[3], d0);
        float d1 = dot2(og1.x, WqpP[0], bqp);
        d1 = dot2(og1.y, WqpP[1], d1);
        d1 = dot2(og1.z, WqpP[2], d1);
        d1 = dot2(og1.w, WqpP[3], d1);
        float d2 = dot2(og2.x, WqpP[0], bqp);
        d2 = dot2(og2.y, WqpP[1], d2);
        d2 = dot2(og2.z, WqpP[2], d2);
        d2 = dot2(og2.w, WqpP[3], d2);
        float d3 = dot2(og3.x, WqpP[0], bqp);
        d3 = dot2(og3.y, WqpP[1], d3);
        d3 = dot2(og3.z, WqpP[2], d3);
        d3 = dot2(og3.w, WqpP[3], d3);
        float fv = fast_sigmoid(d0);
        float iv = fast_sigmoid(d1);
        float gv = fast_tanh(d2);
        float ov = fast_sigmoid(d3);
        cx = fmaf(fv, cx, iv * gv);
        float hmid = ov * fast_tanh(cx);
        u32 pm = pack2(hmid, __shfl_down(hmid, 1));
        if (!(tid & 1)) hmS[(tid >> 3) * 6 + ((tid & 7) >> 1)] = pm;
        __syncthreads();

        // ---- Phase D: attn_in = hmid . W_attn_proj (32 lanes per output) ----
        const u32* mp = &hmS[p * 6];
        uint2 m0 = *(const uint2*)mp;
        uint2 m1 = *(const uint2*)(mp + 2);
        float sD = dot2(m0.x, WapP[0], 0.0f);
        sD = dot2(m0.y, WapP[1], sD);
        sD = dot2(m1.x, WapP[2], sD);
        sD = dot2(m1.y, WapP[3], sD);
        sD += __shfl_xor(sD, 1);
        sD += __shfl_xor(sD, 2);
        sD += __shfl_xor(sD, 4);
        sD += __shfl_xor(sD, 8);
        sD += __shfl_xor(sD, 16);
        if (p == 0) caS[o] = __cosf(sD + bap);
        __syncthreads();

        // ---- Phase E: hx = qgate(attn) @ W_attn_back + b ----
        {
            float4 cA = *(const float4*)&caS[0];
            float4 cB = *(const float4*)&caS[4];
            hx_new = group_dot(cA, cB, Wab) + bab;
        }
        out[((size_t)t * BATCH + b) * HDIM + tid] = hx_new;
        u32 ph = pack2(hx_new, __shfl_down(hx_new, 1));
        if (!(tid & 1)) hS[(tid >> 5) * 20 + ((tid & 31) >> 1)] = ph;
        xpc = xpn;
        __syncthreads();
    }

    const size_t base = (size_t)T_STEPS * BATCH * HDIM;
    out[base + (size_t)b * HDIM + tid] = hx_new;
    out[base + (size_t)BATCH * HDIM + (size_t)b * HDIM + tid] = cx;
}

// ---------------------------------------------------------------------------
// Fallback: round-1 monolithic kernel (used only if ws too small for Xproj)
// ---------------------------------------------------------------------------
__launch_bounds__(256, 2)
__global__ void qlstm_mono(const float* __restrict__ inputs,
                           const float* __restrict__ W_proj,
                           const float* __restrict__ b_proj,
                           const float* __restrict__ theta_gate,
                           const float* __restrict__ W_qproj,
                           const float* __restrict__ b_qproj,
                           const float* __restrict__ theta_attn,
                           const float* __restrict__ W_attn_proj,
                           const float* __restrict__ b_attn_proj,
                           const float* __restrict__ W_attn_back,
                           const float* __restrict__ b_attn_back,
                           float* __restrict__ out) {
    const int tid = threadIdx.x;
    const int b   = blockIdx.x;
    const int g   = tid >> 3;
    const int j   = tid & 7;
    const int o   = tid >> 5;
    const int p   = tid & 31;

    __shared__ __align__(16) float xh[544];
    __shared__ float hm[288];
    __shared__ __align__(16) float cg[32];
    __shared__ __align__(16) float ca[8];

    float Wr[64];
    #pragma unroll
    for (int i = 0; i < 64; ++i)
        Wr[i] = W_proj[(j * 64 + i) * 32 + g];

    float Wqp[8], Wab[8], Wap[8];
    #pragma unroll
    for (int q = 0; q < 8; ++q) {
        Wqp[q] = W_qproj[q * 256 + tid];
        Wab[q] = W_attn_back[q * 256 + tid];
        Wap[q] = W_attn_proj[(p * 8 + q) * 8 + o];
    }
    const float bp  = b_proj[g];
    const float thg = theta_gate[g & 7];
    const float bqp = b_qproj[tid];
    const float bap = b_attn_proj[o];
    const float tha = theta_attn[o];
    const float bab = b_attn_back[tid];

    xh[tid + ((tid >> 6) << 2)] = inputs[(size_t)b * DIN + tid];
    {
        const int k = 256 + tid;
        xh[k + ((k >> 6) << 2)] = 0.0f;
    }
    float cx = 0.0f;
    float hx_new = 0.0f;
    __syncthreads();

    for (int t = 0; t < T_STEPS; ++t) {
        float xn = 0.0f;
        if (t + 1 < T_STEPS)
            xn = inputs[((size_t)(t + 1) * BATCH + b) * DIN + tid];

        float acc = 0.0f;
        {
            const float4* xv = reinterpret_cast<const float4*>(&xh[j * 68]);
            #pragma unroll
            for (int i4 = 0; i4 < 16; ++i4) {
                float4 v = xv[i4];
                acc = fmaf(Wr[4 * i4 + 0], v.x, acc);
                acc = fmaf(Wr[4 * i4 + 1], v.y, acc);
                acc = fmaf(Wr[4 * i4 + 2], v.z, acc);
                acc = fmaf(Wr[4 * i4 + 3], v.w, acc);
            }
        }
        acc += __shfl_xor(acc, 1);
        acc += __shfl_xor(acc, 2);
        acc += __shfl_xor(acc, 4);
        if (j == 0)
            cg[g] = __cosf(acc + bp + thg);
        __syncthreads();

        float dots[4];
        #pragma unroll
        for (int G = 0; G < 4; ++G) {
            float4 cA = *reinterpret_cast<const float4*>(&cg[G * 8]);
            float4 cB = *reinterpret_cast<const float4*>(&cg[G * 8 + 4]);
            dots[G] = group_dot(cA, cB, Wqp) + bqp;
        }
        float fv = fast_sigmoid(dots[0]);
        float iv = fast_sigmoid(dots[1]);
        float gv = fast_tanh(dots[2]);
        float ov = fast_sigmoid(dots[3]);
        cx = fmaf(fv, cx, iv * gv);
        float hmid = ov * fast_tanh(cx);
        hm[tid + (tid >> 3)] = hmid;
        __syncthreads();

        float s = 0.0f;
        #pragma unroll
        for (int m = 0; m < 8; ++m)
            s = fmaf(Wap[m], hm[p * 9 + m], s);
        s += __shfl_xor(s, 1);
        s += __shfl_xor(s, 2);
        s += __shfl_xor(s, 4);
        s += __shfl_xor(s, 8);
        s += __shfl_xor(s, 16);
        if (p == 0)
            ca[o] = __cosf(s + bap + tha);
        __syncthreads();

        {
            float4 cA = *reinterpret_cast<const float4*>(&ca[0]);
            float4 cB = *reinterpret_cast<const float4*>(&ca[4]);
            hx_new = group_dot(cA, cB, Wab) + bab;
        }
        out[((size_t)t * BATCH + b) * HDIM + tid] = hx_new;
        {
            const int k = 256 + tid;
            xh[k + ((k >> 6) << 2)] = hx_new;
        }
        if (t + 1 < T_STEPS)
            xh[tid + ((tid >> 6) << 2)] = xn;
        __syncthreads();
    }

    const size_t base = (size_t)T_STEPS * BATCH * HDIM;
    out[base + (size_t)b * HDIM + tid] = hx_new;
    out[base + (size_t)BATCH * HDIM + (size_t)b * HDIM + tid] = cx;
}

extern "C" void kernel_launch(void* const* d_in, const int* in_sizes, int n_in,
                              void* d_out, int out_size, void* d_ws, size_t ws_size,
                              hipStream_t stream) {
    const float* inputs      = (const float*)d_in[0];
    const float* W_proj      = (const float*)d_in[1];
    const float* b_proj      = (const float*)d_in[2];
    const float* theta_gate  = (const float*)d_in[3];
    const float* W_qproj     = (const float*)d_in[4];
    const float* b_qproj     = (const float*)d_in[5];
    const float* theta_attn  = (const float*)d_in[6];
    const float* W_attn_proj = (const float*)d_in[7];
    const float* b_attn_proj = (const float*)d_in[8];
    const float* W_attn_back = (const float*)d_in[9];
    const float* b_attn_back = (const float*)d_in[10];
    float* outp = (float*)d_out;

    const size_t need = (size_t)T_STEPS * BATCH * 32 * sizeof(float);  // 16.8 MB
    if (ws_size >= need) {
        float* xp = (float*)d_ws;
        xproj_kernel<<<(T_STEPS * BATCH) / 64, 256, 0, stream>>>(
            inputs, W_proj, b_proj, theta_gate, xp);
        qlstm_main<<<BATCH, 256, 0, stream>>>(
            xp, W_proj, W_qproj, b_qproj, theta_attn,
            W_attn_proj, b_attn_proj, W_attn_back, b_attn_back, outp);
    } else {
        qlstm_mono<<<BATCH, 256, 0, stream>>>(
            inputs, W_proj, b_proj, theta_gate, W_qproj, b_qproj, theta_attn,
            W_attn_proj, b_attn_proj, W_attn_back, b_attn_back, outp);
    }
}

// Round 3
// 498.270 us; speedup vs baseline: 1.6170x; 1.6170x over previous
//
#include <hip/hip_runtime.h>

#define T_STEPS 256
#define BATCH   512
#define DIN     256
#define HDIM    256

typedef unsigned int u32;
typedef _Float16 h2 __attribute__((ext_vector_type(2)));

__device__ __forceinline__ u32 pack2(float a, float b) {
    return __builtin_bit_cast(u32, __builtin_amdgcn_cvt_pkrtz(a, b));
}
__device__ __forceinline__ float dot2(u32 a, u32 b, float acc) {
    return __builtin_amdgcn_fdot2(__builtin_bit_cast(h2, a),
                                  __builtin_bit_cast(h2, b), acc, false);
}
__device__ __forceinline__ float fast_sigmoid(float x) {
    return 1.0f / (1.0f + __expf(-x));
}
__device__ __forceinline__ float fast_tanh(float x) {
    return 1.0f - 2.0f / (__expf(2.0f * x) + 1.0f);
}

// ---------------------------------------------------------------------------
// Kernel 1: xp[row][g] = x_row . Wx[:,g] + b_proj[g] + theta_gate[g&7]
// row = t*BATCH + b. LDS-staged f16 x-tile (XOR-swizzled), W column in regs,
// no shuffles, 4 independent fdot2 chains -> memory-bound (~21 us floor).
// ---------------------------------------------------------------------------
__launch_bounds__(256, 1)
__global__ void xproj_kernel(const float* __restrict__ x,
                             const float* __restrict__ W_proj,
                             const float* __restrict__ b_proj,
                             const float* __restrict__ theta_gate,
                             float* __restrict__ xp) {
    const int tid   = threadIdx.x;
    const int g     = tid & 31;     // gate 0..31
    const int rs    = tid >> 5;     // row slot 0..7
    const int rows0 = blockIdx.x * 64;
    __shared__ __align__(16) u32 xs[64 * 128];   // 64 rows x 256 f16 (32 KB)

    // full gate column of the x-part of W_proj, f16-packed: 128 u32
    u32 Wc[128];
    #pragma unroll
    for (int i = 0; i < 128; ++i)
        Wc[i] = pack2(W_proj[(2 * i) * 32 + g], W_proj[(2 * i + 1) * 32 + g]);
    const float bias = b_proj[g] + theta_gate[g & 7];

    // stage 64 rows f32 -> f16 (coalesced), chunk-XOR swizzle vs row
    {
        const int r  = tid >> 2;
        const int c0 = (tid & 3) * 8;   // 8 uint4-chunks of 8 f16 each
        const float* xr = x + (size_t)(rows0 + r) * DIN + c0 * 8;
        #pragma unroll
        for (int w = 0; w < 8; ++w) {
            float4 a = ((const float4*)xr)[2 * w];
            float4 b = ((const float4*)xr)[2 * w + 1];
            uint4 pk = make_uint4(pack2(a.x, a.y), pack2(a.z, a.w),
                                  pack2(b.x, b.y), pack2(b.z, b.w));
            *(uint4*)&xs[r * 128 + ((c0 + w) ^ (r & 7)) * 4] = pk;
        }
    }
    __syncthreads();

    #pragma unroll 1
    for (int it = 0; it < 8; ++it) {
        const int row = it * 8 + rs;
        const u32* xrow = &xs[row * 128];
        const int sw = row & 7;
        float a0 = 0.f, a1 = 0.f, a2 = 0.f, a3 = 0.f;
        #pragma unroll
        for (int c = 0; c < 32; c += 4) {
            uint4 v0 = *(const uint4*)&xrow[((c + 0) ^ sw) * 4];
            uint4 v1 = *(const uint4*)&xrow[((c + 1) ^ sw) * 4];
            uint4 v2 = *(const uint4*)&xrow[((c + 2) ^ sw) * 4];
            uint4 v3 = *(const uint4*)&xrow[((c + 3) ^ sw) * 4];
            a0 = dot2(v0.x, Wc[(c+0)*4+0], a0); a0 = dot2(v0.y, Wc[(c+0)*4+1], a0);
            a0 = dot2(v0.z, Wc[(c+0)*4+2], a0); a0 = dot2(v0.w, Wc[(c+0)*4+3], a0);
            a1 = dot2(v1.x, Wc[(c+1)*4+0], a1); a1 = dot2(v1.y, Wc[(c+1)*4+1], a1);
            a1 = dot2(v1.z, Wc[(c+1)*4+2], a1); a1 = dot2(v1.w, Wc[(c+1)*4+3], a1);
            a2 = dot2(v2.x, Wc[(c+2)*4+0], a2); a2 = dot2(v2.y, Wc[(c+2)*4+1], a2);
            a2 = dot2(v2.z, Wc[(c+2)*4+2], a2); a2 = dot2(v2.w, Wc[(c+2)*4+3], a2);
            a3 = dot2(v3.x, Wc[(c+3)*4+0], a3); a3 = dot2(v3.y, Wc[(c+3)*4+1], a3);
            a3 = dot2(v3.z, Wc[(c+3)*4+2], a3); a3 = dot2(v3.w, Wc[(c+3)*4+3], a3);
        }
        xp[(size_t)(rows0 + row) * 32 + g] = (a0 + a1) + (a2 + a3) + bias;
    }
}

// ---------------------------------------------------------------------------
// Kernel 2: recurrent core. ONE WAVE per batch element -> zero barriers,
// all reductions intra-wave. Lane l owns h-dims 4l..4l+3; weights in regs.
// ---------------------------------------------------------------------------
__launch_bounds__(64, 1)
__global__ void qlstm_main(const float* __restrict__ xp_all,
                           const float* __restrict__ W_proj,
                           const float* __restrict__ W_qproj,
                           const float* __restrict__ b_qproj,
                           const float* __restrict__ theta_attn,
                           const float* __restrict__ W_attn_proj,
                           const float* __restrict__ b_attn_proj,
                           const float* __restrict__ W_attn_back,
                           const float* __restrict__ b_attn_back,
                           float* __restrict__ out) {
    const int l    = threadIdx.x;    // 0..63
    const int b    = blockIdx.x;
    const int g    = l & 31;         // gate (phase A)
    const int half = l >> 5;         // h-half (phase A)
    const int q    = g & 7;          // qubit within group
    const int o    = l >> 3;         // attn output (phase D)
    const int r    = l & 7;          // attn h-chunk (phase D)

    __shared__ __align__(16) u32 hS[128];    // h   f16[256]
    __shared__ __align__(16) u32 hmS[160];   // hmid f16[256], stride 20/chunk
    __shared__ __align__(16) u32 ogS[16];    // 32 gate products, f16

    // ---- register-resident weights (f16-packed) ----
    u32 WhP[64];                     // h-part of W_proj: this gate, this half
    #pragma unroll
    for (int i = 0; i < 64; ++i) {
        int k = half * 128 + 2 * i;
        WhP[i] = pack2(W_proj[(DIN + k) * 32 + g], W_proj[(DIN + k + 1) * 32 + g]);
    }
    u32 WqpP[4][4];                  // [h-sub][q-pair]
    #pragma unroll
    for (int i = 0; i < 4; ++i)
        #pragma unroll
        for (int p = 0; p < 4; ++p)
            WqpP[i][p] = pack2(W_qproj[(2*p) * HDIM + 4*l + i],
                               W_qproj[(2*p+1) * HDIM + 4*l + i]);
    u32 WapP[16];                    // W_attn_proj[32r..32r+31][o]
    #pragma unroll
    for (int i = 0; i < 16; ++i)
        WapP[i] = pack2(W_attn_proj[(32*r + 2*i) * 8 + o],
                        W_attn_proj[(32*r + 2*i + 1) * 8 + o]);
    u32 WabP[4][4];                  // [h-sub][q-pair]
    #pragma unroll
    for (int i = 0; i < 4; ++i)
        #pragma unroll
        for (int p = 0; p < 4; ++p)
            WabP[i][p] = pack2(W_attn_back[(2*p) * HDIM + 4*l + i],
                               W_attn_back[(2*p+1) * HDIM + 4*l + i]);
    float bqp[4], bab[4];
    #pragma unroll
    for (int i = 0; i < 4; ++i) {
        bqp[i] = b_qproj[4*l + i];
        bab[i] = b_attn_back[4*l + i];
    }
    const float bap = b_attn_proj[o] + theta_attn[o];

    // ---- state ----
    float cx[4] = {0.f, 0.f, 0.f, 0.f};
    float hx[4] = {0.f, 0.f, 0.f, 0.f};
    hS[2*l]     = 0u;
    hS[2*l + 1] = 0u;
    float xpc = xp_all[(size_t)b * 32 + g];
    __syncthreads();

    for (int t = 0; t < T_STEPS; ++t) {
        float xpn = 0.f;
        if (t + 1 < T_STEPS)
            xpn = xp_all[((size_t)(t + 1) * BATCH + b) * 32 + g];

        // ---- Phase A: gate preactivation = h . Wh + xp (2 lanes/gate) ----
        const u32* hp = &hS[half * 64];
        float a0 = 0.f, a1 = 0.f, a2 = 0.f, a3 = 0.f;
        #pragma unroll
        for (int c = 0; c < 4; ++c) {
            uint4 v0 = ((const uint4*)hp)[c*4 + 0];
            uint4 v1 = ((const uint4*)hp)[c*4 + 1];
            uint4 v2 = ((const uint4*)hp)[c*4 + 2];
            uint4 v3 = ((const uint4*)hp)[c*4 + 3];
            a0 = dot2(v0.x, WhP[c*16+ 0], a0); a0 = dot2(v0.y, WhP[c*16+ 1], a0);
            a0 = dot2(v0.z, WhP[c*16+ 2], a0); a0 = dot2(v0.w, WhP[c*16+ 3], a0);
            a1 = dot2(v1.x, WhP[c*16+ 4], a1); a1 = dot2(v1.y, WhP[c*16+ 5], a1);
            a1 = dot2(v1.z, WhP[c*16+ 6], a1); a1 = dot2(v1.w, WhP[c*16+ 7], a1);
            a2 = dot2(v2.x, WhP[c*16+ 8], a2); a2 = dot2(v2.y, WhP[c*16+ 9], a2);
            a2 = dot2(v2.z, WhP[c*16+10], a2); a2 = dot2(v2.w, WhP[c*16+11], a2);
            a3 = dot2(v3.x, WhP[c*16+12], a3); a3 = dot2(v3.y, WhP[c*16+13], a3);
            a3 = dot2(v3.z, WhP[c*16+14], a3); a3 = dot2(v3.w, WhP[c*16+15], a3);
        }
        float acc = (a0 + a1) + (a2 + a3);
        acc += __shfl_xor(acc, 32);
        float cq = __cosf(acc + xpc);

        // prefix products within each 8-lane qubit group
        float s = cq, uu;
        uu = __shfl_up(s, 1, 8); if (q >= 1) s *= uu;
        uu = __shfl_up(s, 2, 8); if (q >= 2) s *= uu;
        uu = __shfl_up(s, 4, 8); if (q >= 4) s *= uu;
        float v = (q == 0) ? 1.0f : cq;      // product excluding c0
        v *= __shfl_xor(v, 1);
        v *= __shfl_xor(v, 2);
        v *= __shfl_xor(v, 4);
        float outv = (q == 0) ? v : s;
        float nxt = __shfl_down(outv, 1);
        if (l < 32 && !(l & 1)) ogS[l >> 1] = pack2(outv, nxt);

        // ---- Phase B/C: qp dots + activations + LSTM cell (4 h/lane) ----
        uint4 og0 = ((const uint4*)ogS)[0];
        uint4 og1 = ((const uint4*)ogS)[1];
        uint4 og2 = ((const uint4*)ogS)[2];
        uint4 og3 = ((const uint4*)ogS)[3];
        float hm4[4];
        #pragma unroll
        for (int i = 0; i < 4; ++i) {
            float d0 = dot2(og0.x, WqpP[i][0], bqp[i]);
            d0 = dot2(og0.y, WqpP[i][1], d0);
            d0 = dot2(og0.z, WqpP[i][2], d0);
            d0 = dot2(og0.w, WqpP[i][3], d0);
            float d1 = dot2(og1.x, WqpP[i][0], bqp[i]);
            d1 = dot2(og1.y, WqpP[i][1], d1);
            d1 = dot2(og1.z, WqpP[i][2], d1);
            d1 = dot2(og1.w, WqpP[i][3], d1);
            float d2 = dot2(og2.x, WqpP[i][0], bqp[i]);
            d2 = dot2(og2.y, WqpP[i][1], d2);
            d2 = dot2(og2.z, WqpP[i][2], d2);
            d2 = dot2(og2.w, WqpP[i][3], d2);
            float d3 = dot2(og3.x, WqpP[i][0], bqp[i]);
            d3 = dot2(og3.y, WqpP[i][1], d3);
            d3 = dot2(og3.z, WqpP[i][2], d3);
            d3 = dot2(og3.w, WqpP[i][3], d3);
            float fv = fast_sigmoid(d0);
            float iv = fast_sigmoid(d1);
            float gv = fast_tanh(d2);
            float ov = fast_sigmoid(d3);
            cx[i] = fmaf(fv, cx[i], iv * gv);
            hm4[i] = ov * fast_tanh(cx[i]);
        }
        // write hmid (padded stride-20 chunks -> conflict-free phase-D reads)
        {
            u32 m0 = pack2(hm4[0], hm4[1]);
            u32 m1 = pack2(hm4[2], hm4[3]);
            *(uint2*)&hmS[(l >> 3) * 20 + ((2 * l) & 15)] = make_uint2(m0, m1);
        }

        // ---- Phase D: attn preact = hmid . Wap (8 lanes per output) ----
        const u32* mp = &hmS[r * 20];
        uint4 w0 = ((const uint4*)mp)[0];
        uint4 w1 = ((const uint4*)mp)[1];
        uint4 w2 = ((const uint4*)mp)[2];
        uint4 w3 = ((const uint4*)mp)[3];
        float sD = dot2(w0.x, WapP[ 0], 0.f);
        sD = dot2(w0.y, WapP[ 1], sD);
        sD = dot2(w0.z, WapP[ 2], sD);
        sD = dot2(w0.w, WapP[ 3], sD);
        sD = dot2(w1.x, WapP[ 4], sD);
        sD = dot2(w1.y, WapP[ 5], sD);
        sD = dot2(w1.z, WapP[ 6], sD);
        sD = dot2(w1.w, WapP[ 7], sD);
        sD = dot2(w2.x, WapP[ 8], sD);
        sD = dot2(w2.y, WapP[ 9], sD);
        sD = dot2(w2.z, WapP[10], sD);
        sD = dot2(w2.w, WapP[11], sD);
        sD = dot2(w3.x, WapP[12], sD);
        sD = dot2(w3.y, WapP[13], sD);
        sD = dot2(w3.z, WapP[14], sD);
        sD = dot2(w3.w, WapP[15], sD);
        sD += __shfl_xor(sD, 1);
        sD += __shfl_xor(sD, 2);
        sD += __shfl_xor(sD, 4);
        float co = __cosf(sD + bap);

        // ---- Phase E: broadcast 8 cosines, prefix, hx = oq . Wab + b ----
        float ca0 = __shfl(co,  0), ca1 = __shfl(co,  8);
        float ca2 = __shfl(co, 16), ca3 = __shfl(co, 24);
        float ca4 = __shfl(co, 32), ca5 = __shfl(co, 40);
        float ca6 = __shfl(co, 48), ca7 = __shfl(co, 56);
        float p1 = ca0 * ca1;
        float p2 = p1 * ca2;
        float p3 = p2 * ca3;
        float p4 = p3 * ca4;
        float p5 = p4 * ca5;
        float p6 = p5 * ca6;
        float p7 = p6 * ca7;
        float p0 = ((ca1 * ca2) * (ca3 * ca4)) * ((ca5 * ca6) * ca7);
        u32 oq0 = pack2(p0, p1);
        u32 oq1 = pack2(p2, p3);
        u32 oq2 = pack2(p4, p5);
        u32 oq3 = pack2(p6, p7);
        #pragma unroll
        for (int i = 0; i < 4; ++i) {
            float hv = dot2(oq0, WabP[i][0], bab[i]);
            hv = dot2(oq1, WabP[i][1], hv);
            hv = dot2(oq2, WabP[i][2], hv);
            hv = dot2(oq3, WabP[i][3], hv);
            hx[i] = hv;
        }
        // store output row + update h in LDS (no barrier: single wave)
        *(float4*)&out[((size_t)t * BATCH + b) * HDIM + 4*l] =
            make_float4(hx[0], hx[1], hx[2], hx[3]);
        hS[2*l]     = pack2(hx[0], hx[1]);
        hS[2*l + 1] = pack2(hx[2], hx[3]);
        xpc = xpn;
    }

    // ---- final (hx, cx) ----
    const size_t base = (size_t)T_STEPS * BATCH * HDIM;
    *(float4*)&out[base + (size_t)b * HDIM + 4*l] =
        make_float4(hx[0], hx[1], hx[2], hx[3]);
    *(float4*)&out[base + (size_t)BATCH * HDIM + (size_t)b * HDIM + 4*l] =
        make_float4(cx[0], cx[1], cx[2], cx[3]);
}

extern "C" void kernel_launch(void* const* d_in, const int* in_sizes, int n_in,
                              void* d_out, int out_size, void* d_ws, size_t ws_size,
                              hipStream_t stream) {
    const float* inputs      = (const float*)d_in[0];
    const float* W_proj      = (const float*)d_in[1];
    const float* b_proj      = (const float*)d_in[2];
    const float* theta_gate  = (const float*)d_in[3];
    const float* W_qproj     = (const float*)d_in[4];
    const float* b_qproj     = (const float*)d_in[5];
    const float* theta_attn  = (const float*)d_in[6];
    const float* W_attn_proj = (const float*)d_in[7];
    const float* b_attn_proj = (const float*)d_in[8];
    const float* W_attn_back = (const float*)d_in[9];
    const float* b_attn_back = (const float*)d_in[10];
    float* outp = (float*)d_out;
    float* xp   = (float*)d_ws;   // 256*512*32 f32 = 16.8 MB (ws verified >= this in r2)

    xproj_kernel<<<(T_STEPS * BATCH) / 64, 256, 0, stream>>>(
        inputs, W_proj, b_proj, theta_gate, xp);
    qlstm_main<<<BATCH, 64, 0, stream>>>(
        xp, W_proj, W_qproj, b_qproj, theta_attn,
        W_attn_proj, b_attn_proj, W_attn_back, b_attn_back, outp);
}

// Round 4
// 423.337 us; speedup vs baseline: 1.9033x; 1.1770x over previous
//
#include <hip/hip_runtime.h>

#define T_STEPS 256
#define BATCH   512
#define DIN     256
#define HDIM    256

typedef unsigned int u32;
typedef _Float16 h2 __attribute__((ext_vector_type(2)));

__device__ __forceinline__ u32 pack2(float a, float b) {
    return __builtin_bit_cast(u32, __builtin_amdgcn_cvt_pkrtz(a, b));
}
__device__ __forceinline__ float dot2(u32 a, u32 b, float acc) {
    return __builtin_amdgcn_fdot2(__builtin_bit_cast(h2, a),
                                  __builtin_bit_cast(h2, b), acc, false);
}
__device__ __forceinline__ float fast_sigmoid(float x) {
    return 1.0f / (1.0f + __expf(-x));
}
__device__ __forceinline__ float fast_tanh(float x) {
    return 1.0f - 2.0f / (__expf(2.0f * x) + 1.0f);
}

// ---------------------------------------------------------------------------
// Kernel 1: xp[row][g] = x_row . Wx[:,g] + b_proj[g] + theta_gate[g&7]
// (unchanged from r3: ~41 us, memory-bound-ish)
// ---------------------------------------------------------------------------
__launch_bounds__(256, 1)
__global__ void xproj_kernel(const float* __restrict__ x,
                             const float* __restrict__ W_proj,
                             const float* __restrict__ b_proj,
                             const float* __restrict__ theta_gate,
                             float* __restrict__ xp) {
    const int tid   = threadIdx.x;
    const int g     = tid & 31;
    const int rs    = tid >> 5;
    const int rows0 = blockIdx.x * 64;
    __shared__ __align__(16) u32 xs[64 * 128];

    u32 Wc[128];
    #pragma unroll
    for (int i = 0; i < 128; ++i)
        Wc[i] = pack2(W_proj[(2 * i) * 32 + g], W_proj[(2 * i + 1) * 32 + g]);
    const float bias = b_proj[g] + theta_gate[g & 7];

    {
        const int r  = tid >> 2;
        const int c0 = (tid & 3) * 8;
        const float* xr = x + (size_t)(rows0 + r) * DIN + c0 * 8;
        #pragma unroll
        for (int w = 0; w < 8; ++w) {
            float4 a = ((const float4*)xr)[2 * w];
            float4 b = ((const float4*)xr)[2 * w + 1];
            uint4 pk = make_uint4(pack2(a.x, a.y), pack2(a.z, a.w),
                                  pack2(b.x, b.y), pack2(b.z, b.w));
            *(uint4*)&xs[r * 128 + ((c0 + w) ^ (r & 7)) * 4] = pk;
        }
    }
    __syncthreads();

    #pragma unroll 1
    for (int it = 0; it < 8; ++it) {
        const int row = it * 8 + rs;
        const u32* xrow = &xs[row * 128];
        const int sw = row & 7;
        float a0 = 0.f, a1 = 0.f, a2 = 0.f, a3 = 0.f;
        #pragma unroll
        for (int c = 0; c < 32; c += 4) {
            uint4 v0 = *(const uint4*)&xrow[((c + 0) ^ sw) * 4];
            uint4 v1 = *(const uint4*)&xrow[((c + 1) ^ sw) * 4];
            uint4 v2 = *(const uint4*)&xrow[((c + 2) ^ sw) * 4];
            uint4 v3 = *(const uint4*)&xrow[((c + 3) ^ sw) * 4];
            a0 = dot2(v0.x, Wc[(c+0)*4+0], a0); a0 = dot2(v0.y, Wc[(c+0)*4+1], a0);
            a0 = dot2(v0.z, Wc[(c+0)*4+2], a0); a0 = dot2(v0.w, Wc[(c+0)*4+3], a0);
            a1 = dot2(v1.x, Wc[(c+1)*4+0], a1); a1 = dot2(v1.y, Wc[(c+1)*4+1], a1);
            a1 = dot2(v1.z, Wc[(c+1)*4+2], a1); a1 = dot2(v1.w, Wc[(c+1)*4+3], a1);
            a2 = dot2(v2.x, Wc[(c+2)*4+0], a2); a2 = dot2(v2.y, Wc[(c+2)*4+1], a2);
            a2 = dot2(v2.z, Wc[(c+2)*4+2], a2); a2 = dot2(v2.w, Wc[(c+2)*4+3], a2);
            a3 = dot2(v3.x, Wc[(c+3)*4+0], a3); a3 = dot2(v3.y, Wc[(c+3)*4+1], a3);
            a3 = dot2(v3.z, Wc[(c+3)*4+2], a3); a3 = dot2(v3.w, Wc[(c+3)*4+3], a3);
        }
        xp[(size_t)(rows0 + row) * 32 + g] = (a0 + a1) + (a2 + a3) + bias;
    }
}

// ---------------------------------------------------------------------------
// Kernel 2: recurrent core. 4 waves per batch element (wave = gate-type),
// 3 barriers/step, padded stride-20 LDS (conflict-free b128), f16 dot2.
// ---------------------------------------------------------------------------
__launch_bounds__(256, 2)
__global__ void qlstm_main(const float* __restrict__ xp_all,
                           const float* __restrict__ W_proj,
                           const float* __restrict__ W_qproj,
                           const float* __restrict__ b_qproj,
                           const float* __restrict__ theta_attn,
                           const float* __restrict__ W_attn_proj,
                           const float* __restrict__ b_attn_proj,
                           const float* __restrict__ W_attn_back,
                           const float* __restrict__ b_attn_back,
                           float* __restrict__ out) {
    const int tid = threadIdx.x;
    const int b   = blockIdx.x;
    const int w   = tid >> 6;      // wave index = gate-type (f,i,g,o)
    const int lw  = tid & 63;      // lane in wave
    const int q   = lw >> 3;       // qubit 0..7 (phase A) / attn output (phase D)
    const int j   = tid & 7;       // 32-dim h-chunk (phases A, D)
    const int g   = tid >> 3;      // global gate index 0..31 (= w*8+q)

    // stride-20 padded chunks: chunk j at u32 offset j*20 -> 8 disjoint bank quads
    __shared__ __align__(16) u32 hS[160];     // h,   f16[256]
    __shared__ __align__(16) u32 hmS[160];    // hmid f16[256]
    __shared__ __align__(16) u32 ogS[16];     // 32 gate Z-products, f16 pairs
    __shared__ __align__(16) float caS[32];   // 8 attn cosines, per-wave copy

    // ---- register-resident weights ----
    u32 WhP[16];                   // W_proj h-part: column g, dims 32j..32j+31
    #pragma unroll
    for (int i = 0; i < 16; ++i)
        WhP[i] = pack2(W_proj[(DIN + j * 32 + 2 * i) * 32 + g],
                       W_proj[(DIN + j * 32 + 2 * i + 1) * 32 + g]);
    u32 WqpP[4];                   // W_qproj column tid (shared by all 4 types)
    #pragma unroll
    for (int p = 0; p < 4; ++p)
        WqpP[p] = pack2(W_qproj[(2 * p) * HDIM + tid],
                        W_qproj[(2 * p + 1) * HDIM + tid]);
    u32 WapP[16];                  // W_attn_proj: dims 32j.., output q
    #pragma unroll
    for (int i = 0; i < 16; ++i)
        WapP[i] = pack2(W_attn_proj[(32 * j + 2 * i) * 8 + q],
                        W_attn_proj[(32 * j + 2 * i + 1) * 8 + q]);
    u32 WabP[4];                   // W_attn_back column tid
    #pragma unroll
    for (int p = 0; p < 4; ++p)
        WabP[p] = pack2(W_attn_back[(2 * p) * HDIM + tid],
                        W_attn_back[(2 * p + 1) * HDIM + tid]);
    const float bqp = b_qproj[tid];
    const float bap = b_attn_proj[q] + theta_attn[q];
    const float bab = b_attn_back[tid];

    if (tid < 160) hS[tid] = 0u;
    float cx = 0.f, hx = 0.f;
    float xpc = xp_all[(size_t)b * 32 + g];
    __syncthreads();

    for (int t = 0; t < T_STEPS; ++t) {
        // ---- Phase A: gate preactivation (8 lanes/gate x 32 dims) ----
        const u32* hp = &hS[j * 20];
        uint4 v0 = ((const uint4*)hp)[0];
        uint4 v1 = ((const uint4*)hp)[1];
        uint4 v2 = ((const uint4*)hp)[2];
        uint4 v3 = ((const uint4*)hp)[3];
        float a0 = dot2(v0.x, WhP[ 0], 0.f);
        a0 = dot2(v0.y, WhP[ 1], a0);
        a0 = dot2(v0.z, WhP[ 2], a0);
        a0 = dot2(v0.w, WhP[ 3], a0);
        float a1 = dot2(v1.x, WhP[ 4], 0.f);
        a1 = dot2(v1.y, WhP[ 5], a1);
        a1 = dot2(v1.z, WhP[ 6], a1);
        a1 = dot2(v1.w, WhP[ 7], a1);
        float a2 = dot2(v2.x, WhP[ 8], 0.f);
        a2 = dot2(v2.y, WhP[ 9], a2);
        a2 = dot2(v2.z, WhP[10], a2);
        a2 = dot2(v2.w, WhP[11], a2);
        float a3 = dot2(v3.x, WhP[12], 0.f);
        a3 = dot2(v3.y, WhP[13], a3);
        a3 = dot2(v3.z, WhP[14], a3);
        a3 = dot2(v3.w, WhP[15], a3);
        float acc = (a0 + a1) + (a2 + a3);
        acc += __shfl_xor(acc, 1);
        acc += __shfl_xor(acc, 2);
        acc += __shfl_xor(acc, 4);
        float cq = __cosf(acc + xpc);

        // prefix products over qubits (stride 8 within wave)
        float s = cq, uu;
        uu = __shfl_up(s, 8);  if (q >= 1) s *= uu;
        uu = __shfl_up(s, 16); if (q >= 2) s *= uu;
        uu = __shfl_up(s, 32); if (q >= 4) s *= uu;
        float v = (q == 0) ? 1.0f : cq;       // product excluding c0
        v *= __shfl_xor(v, 8);
        v *= __shfl_xor(v, 16);
        v *= __shfl_xor(v, 32);
        float outv = (q == 0) ? v : s;
        float nxt = __shfl_down(outv, 8);
        if ((lw & 15) == 0)                    // q even, j == 0
            ogS[w * 4 + (lw >> 4)] = pack2(outv, nxt);
        __syncthreads();                       // barrier 1

        // ---- Phase B/C: qp dots + activations + LSTM cell (lane = h-dim) ----
        uint4 og0 = ((const uint4*)ogS)[0];
        uint4 og1 = ((const uint4*)ogS)[1];
        uint4 og2 = ((const uint4*)ogS)[2];
        uint4 og3 = ((const uint4*)ogS)[3];
        // prefetch next xp row (used next iteration, hidden under D/E)
        float xpn = 0.f;
        if (t + 1 < T_STEPS)
            xpn = xp_all[((size_t)(t + 1) * BATCH + b) * 32 + g];
        float d0 = dot2(og0.x, WqpP[0], bqp);
        d0 = dot2(og0.y, WqpP[1], d0);
        d0 = dot2(og0.z, WqpP[2], d0);
        d0 = dot2(og0.w, WqpP[3], d0);
        float d1 = dot2(og1.x, WqpP[0], bqp);
        d1 = dot2(og1.y, WqpP[1], d1);
        d1 = dot2(og1.z, WqpP[2], d1);
        d1 = dot2(og1.w, WqpP[3], d1);
        float d2 = dot2(og2.x, WqpP[0], bqp);
        d2 = dot2(og2.y, WqpP[1], d2);
        d2 = dot2(og2.z, WqpP[2], d2);
        d2 = dot2(og2.w, WqpP[3], d2);
        float d3 = dot2(og3.x, WqpP[0], bqp);
        d3 = dot2(og3.y, WqpP[1], d3);
        d3 = dot2(og3.z, WqpP[2], d3);
        d3 = dot2(og3.w, WqpP[3], d3);
        float fv = fast_sigmoid(d0);
        float iv = fast_sigmoid(d1);
        float gv = fast_tanh(d2);
        float ov = fast_sigmoid(d3);
        cx = fmaf(fv, cx, iv * gv);
        float hm = ov * fast_tanh(cx);
        u32 pm = pack2(hm, __shfl_down(hm, 1));
        if (!(tid & 1))
            hmS[(tid >> 5) * 20 + ((tid >> 1) & 15)] = pm;
        __syncthreads();                       // barrier 2

        // ---- Phase D: attn projection, computed redundantly per wave ----
        const u32* mp = &hmS[j * 20];
        uint4 m0 = ((const uint4*)mp)[0];
        uint4 m1 = ((const uint4*)mp)[1];
        uint4 m2 = ((const uint4*)mp)[2];
        uint4 m3 = ((const uint4*)mp)[3];
        float s0 = dot2(m0.x, WapP[ 0], 0.f);
        s0 = dot2(m0.y, WapP[ 1], s0);
        s0 = dot2(m0.z, WapP[ 2], s0);
        s0 = dot2(m0.w, WapP[ 3], s0);
        float s1 = dot2(m1.x, WapP[ 4], 0.f);
        s1 = dot2(m1.y, WapP[ 5], s1);
        s1 = dot2(m1.z, WapP[ 6], s1);
        s1 = dot2(m1.w, WapP[ 7], s1);
        float s2 = dot2(m2.x, WapP[ 8], 0.f);
        s2 = dot2(m2.y, WapP[ 9], s2);
        s2 = dot2(m2.z, WapP[10], s2);
        s2 = dot2(m2.w, WapP[11], s2);
        float s3 = dot2(m3.x, WapP[12], 0.f);
        s3 = dot2(m3.y, WapP[13], s3);
        s3 = dot2(m3.z, WapP[14], s3);
        s3 = dot2(m3.w, WapP[15], s3);
        float sd = (s0 + s1) + (s2 + s3);
        sd += __shfl_xor(sd, 1);
        sd += __shfl_xor(sd, 2);
        sd += __shfl_xor(sd, 4);
        float co = __cosf(sd + bap);
        if (j == 0) caS[w * 8 + q] = co;       // per-wave copy, no barrier

        // ---- Phase E: hx = attn-qgate . W_attn_back + b (lane = h-dim) ----
        float4 cA = *(const float4*)&caS[w * 8];
        float4 cB = *(const float4*)&caS[w * 8 + 4];
        float p1 = cA.x * cA.y;
        float p2 = p1 * cA.z;
        float p3 = p2 * cA.w;
        float p4 = p3 * cB.x;
        float p5 = p4 * cB.y;
        float p6 = p5 * cB.z;
        float p7 = p6 * cB.w;
        float q12 = cA.y * cA.z, q34 = cA.w * cB.x, q56 = cB.y * cB.z;
        float p0 = (q12 * q34) * (q56 * cB.w);
        u32 oq0 = pack2(p0, p1);
        u32 oq1 = pack2(p2, p3);
        u32 oq2 = pack2(p4, p5);
        u32 oq3 = pack2(p6, p7);
        float hv = dot2(oq0, WabP[0], bab);
        hv = dot2(oq1, WabP[1], hv);
        hv = dot2(oq2, WabP[2], hv);
        hv = dot2(oq3, WabP[3], hv);
        hx = hv;
        out[((size_t)t * BATCH + b) * HDIM + tid] = hx;
        u32 ph = pack2(hx, __shfl_down(hx, 1));
        if (!(tid & 1))
            hS[(tid >> 5) * 20 + ((tid >> 1) & 15)] = ph;
        xpc = xpn;
        __syncthreads();                       // barrier 3
    }

    const size_t base = (size_t)T_STEPS * BATCH * HDIM;
    out[base + (size_t)b * HDIM + tid] = hx;
    out[base + (size_t)BATCH * HDIM + (size_t)b * HDIM + tid] = cx;
}

extern "C" void kernel_launch(void* const* d_in, const int* in_sizes, int n_in,
                              void* d_out, int out_size, void* d_ws, size_t ws_size,
                              hipStream_t stream) {
    const float* inputs      = (const float*)d_in[0];
    const float* W_proj      = (const float*)d_in[1];
    const float* b_proj      = (const float*)d_in[2];
    const float* theta_gate  = (const float*)d_in[3];
    const float* W_qproj     = (const float*)d_in[4];
    const float* b_qproj     = (const float*)d_in[5];
    const float* theta_attn  = (const float*)d_in[6];
    const float* W_attn_proj = (const float*)d_in[7];
    const float* b_attn_proj = (const float*)d_in[8];
    const float* W_attn_back = (const float*)d_in[9];
    const float* b_attn_back = (const float*)d_in[10];
    float* outp = (float*)d_out;
    float* xp   = (float*)d_ws;   // 256*512*32 f32 = 16.8 MB

    xproj_kernel<<<(T_STEPS * BATCH) / 64, 256, 0, stream>>>(
        inputs, W_proj, b_proj, theta_gate, xp);
    qlstm_main<<<BATCH, 256, 0, stream>>>(
        xp, W_proj, W_qproj, b_qproj, theta_attn,
        W_attn_proj, b_attn_proj, W_attn_back, b_attn_back, outp);
}

// Round 6
// 382.856 us; speedup vs baseline: 2.1045x; 1.1057x over previous
//
#include <hip/hip_runtime.h>

#define T_STEPS 256
#define BATCH   512
#define DIN     256
#define HDIM    256

typedef unsigned int u32;
typedef _Float16 h2 __attribute__((ext_vector_type(2)));

__device__ __forceinline__ u32 pack2(float a, float b) {
    return __builtin_bit_cast(u32, __builtin_amdgcn_cvt_pkrtz(a, b));
}
__device__ __forceinline__ float dot2(u32 a, u32 b, float acc) {
    return __builtin_amdgcn_fdot2(__builtin_bit_cast(h2, a),
                                  __builtin_bit_cast(h2, b), acc, false);
}
__device__ __forceinline__ float rcpf(float x) { return __builtin_amdgcn_rcpf(x); }
__device__ __forceinline__ float fast_sigmoid(float x) {
    return rcpf(1.0f + __expf(-x));
}
__device__ __forceinline__ float fast_tanh(float x) {
    return 1.0f - 2.0f * rcpf(__expf(2.0f * x) + 1.0f);
}

// DPP lane permute (VALU, not DS pipe). Invalid lanes keep own value.
template<int CTRL>
__device__ __forceinline__ float dppf(float x) {
    int xi = __builtin_bit_cast(int, x);
    return __builtin_bit_cast(float,
        __builtin_amdgcn_update_dpp(xi, xi, CTRL, 0xF, 0xF, false));
}
#define DPP_XOR1  0xB1   // quad_perm [1,0,3,2]
#define DPP_XOR2  0x4E   // quad_perm [2,3,0,1]
#define DPP_HMIR  0x141  // row_half_mirror (other quad within 8-group)
#define DPP_SHR1  0x111  // lane i <- i-1
#define DPP_SHR2  0x112
#define DPP_SHR4  0x114
#define DPP_SHL1  0x101  // lane i <- i+1

// LDS-only barrier: don't drain vmcnt (global store / xp prefetch stay in flight)
__device__ __forceinline__ void lds_barrier() {
    asm volatile("s_waitcnt lgkmcnt(0)\n\ts_barrier" ::: "memory");
}

// ---------------------------------------------------------------------------
// Kernel 1: xp[row][g] = x_row . Wx[:,g] + b_proj[g] + theta_gate[g&7]
// (unchanged from r4: ~41 us)
// ---------------------------------------------------------------------------
__launch_bounds__(256, 1)
__global__ void xproj_kernel(const float* __restrict__ x,
                             const float* __restrict__ W_proj,
                             const float* __restrict__ b_proj,
                             const float* __restrict__ theta_gate,
                             float* __restrict__ xp) {
    const int tid   = threadIdx.x;
    const int g     = tid & 31;
    const int rs    = tid >> 5;
    const int rows0 = blockIdx.x * 64;
    __shared__ __align__(16) u32 xs[64 * 128];

    u32 Wc[128];
    #pragma unroll
    for (int i = 0; i < 128; ++i)
        Wc[i] = pack2(W_proj[(2 * i) * 32 + g], W_proj[(2 * i + 1) * 32 + g]);
    const float bias = b_proj[g] + theta_gate[g & 7];

    {
        const int r  = tid >> 2;
        const int c0 = (tid & 3) * 8;
        const float* xr = x + (size_t)(rows0 + r) * DIN + c0 * 8;
        #pragma unroll
        for (int w = 0; w < 8; ++w) {
            float4 a = ((const float4*)xr)[2 * w];
            float4 b = ((const float4*)xr)[2 * w + 1];
            uint4 pk = make_uint4(pack2(a.x, a.y), pack2(a.z, a.w),
                                  pack2(b.x, b.y), pack2(b.z, b.w));
            *(uint4*)&xs[r * 128 + ((c0 + w) ^ (r & 7)) * 4] = pk;
        }
    }
    __syncthreads();

    #pragma unroll 1
    for (int it = 0; it < 8; ++it) {
        const int row = it * 8 + rs;
        const u32* xrow = &xs[row * 128];
        const int sw = row & 7;
        float a0 = 0.f, a1 = 0.f, a2 = 0.f, a3 = 0.f;
        #pragma unroll
        for (int c = 0; c < 32; c += 4) {
            uint4 v0 = *(const uint4*)&xrow[((c + 0) ^ sw) * 4];
            uint4 v1 = *(const uint4*)&xrow[((c + 1) ^ sw) * 4];
            uint4 v2 = *(const uint4*)&xrow[((c + 2) ^ sw) * 4];
            uint4 v3 = *(const uint4*)&xrow[((c + 3) ^ sw) * 4];
            a0 = dot2(v0.x, Wc[(c+0)*4+0], a0); a0 = dot2(v0.y, Wc[(c+0)*4+1], a0);
            a0 = dot2(v0.z, Wc[(c+0)*4+2], a0); a0 = dot2(v0.w, Wc[(c+0)*4+3], a0);
            a1 = dot2(v1.x, Wc[(c+1)*4+0], a1); a1 = dot2(v1.y, Wc[(c+1)*4+1], a1);
            a1 = dot2(v1.z, Wc[(c+1)*4+2], a1); a1 = dot2(v1.w, Wc[(c+1)*4+3], a1);
            a2 = dot2(v2.x, Wc[(c+2)*4+0], a2); a2 = dot2(v2.y, Wc[(c+2)*4+1], a2);
            a2 = dot2(v2.z, Wc[(c+2)*4+2], a2); a2 = dot2(v2.w, Wc[(c+2)*4+3], a2);
            a3 = dot2(v3.x, Wc[(c+3)*4+0], a3); a3 = dot2(v3.y, Wc[(c+3)*4+1], a3);
            a3 = dot2(v3.z, Wc[(c+3)*4+2], a3); a3 = dot2(v3.w, Wc[(c+3)*4+3], a3);
        }
        xp[(size_t)(rows0 + row) * 32 + g] = (a0 + a1) + (a2 + a3) + bias;
    }
}

// ---------------------------------------------------------------------------
// Kernel 2: recurrent core. 4 waves/batch-element; phase A wave-redundant
// (gate = lane&31, 2 lanes/gate covering 128 dims EACH — FULL dot this time),
// og per-wave, 2 lgkm-only barriers/step, all cross-lane via DPP except one
// xor32 shuffle.
// ---------------------------------------------------------------------------
__launch_bounds__(256, 2)
__global__ void qlstm_main(const float* __restrict__ xp_all,
                           const float* __restrict__ W_proj,
                           const float* __restrict__ W_qproj,
                           const float* __restrict__ b_qproj,
                           const float* __restrict__ theta_attn,
                           const float* __restrict__ W_attn_proj,
                           const float* __restrict__ b_attn_proj,
                           const float* __restrict__ W_attn_back,
                           const float* __restrict__ b_attn_back,
                           float* __restrict__ out) {
    const int tid  = threadIdx.x;
    const int b    = blockIdx.x;
    const int w    = tid >> 6;      // wave 0..3
    const int lw   = tid & 63;      // lane in wave
    const int g    = lw & 31;       // gate 0..31 (phase A)
    const int half = lw >> 5;       // h-half for phase-A dot
    const int q    = lw & 7;        // qubit within gate group (A) / chunk (D)
    const int o    = lw >> 3;       // attn output (D/E)

    __shared__ __align__(16) u32 hS[128];    // h    f16[256]
    __shared__ __align__(16) u32 hmS[160];   // hmid f16[256], stride-20 chunks
    __shared__ __align__(16) u32 ogS[64];    // 4 waves x 16 u32 (32 gate prods)
    __shared__ __align__(16) float caS[32];  // 4 waves x 8 attn cosines

    // ---- register-resident weights ----
    u32 WhP[64];                    // W_proj h-part col g, dims half*128..+127
    #pragma unroll
    for (int i = 0; i < 64; ++i) {
        int k = half * 128 + 2 * i;
        WhP[i] = pack2(W_proj[(DIN + k) * 32 + g], W_proj[(DIN + k + 1) * 32 + g]);
    }
    u32 WqpP[4];
    #pragma unroll
    for (int p = 0; p < 4; ++p)
        WqpP[p] = pack2(W_qproj[(2 * p) * HDIM + tid],
                        W_qproj[(2 * p + 1) * HDIM + tid]);
    u32 WapP[16];                   // W_attn_proj dims 32q.., output o
    #pragma unroll
    for (int i = 0; i < 16; ++i)
        WapP[i] = pack2(W_attn_proj[(32 * q + 2 * i) * 8 + o],
                        W_attn_proj[(32 * q + 2 * i + 1) * 8 + o]);
    u32 WabP[4];
    #pragma unroll
    for (int p = 0; p < 4; ++p)
        WabP[p] = pack2(W_attn_back[(2 * p) * HDIM + tid],
                        W_attn_back[(2 * p + 1) * HDIM + tid]);
    const float bqp = b_qproj[tid];
    const float bap = b_attn_proj[o] + theta_attn[o];
    const float bab = b_attn_back[tid];

    if (tid < 128) hS[tid] = 0u;
    float cx = 0.f, hx = 0.f;
    float xpc = xp_all[(size_t)b * 32 + g];
    __syncthreads();

    for (int t = 0; t < T_STEPS; ++t) {
        float xpn = 0.f;
        if (t + 1 < T_STEPS)
            xpn = xp_all[((size_t)(t + 1) * BATCH + b) * 32 + g];

        // ---- Phase A (wave-redundant): 32 gates, 2 lanes/gate, FULL 128-dim
        //      half-dot per lane (16 x uint4 broadcast reads, 64 dot2) ----
        const uint4* hp = (const uint4*)&hS[half * 64];
        float a0 = 0.f, a1 = 0.f, a2 = 0.f, a3 = 0.f;
        #pragma unroll
        for (int c = 0; c < 16; ++c) {
            uint4 vv = hp[c];
            a0 = dot2(vv.x, WhP[4 * c + 0], a0);
            a1 = dot2(vv.y, WhP[4 * c + 1], a1);
            a2 = dot2(vv.z, WhP[4 * c + 2], a2);
            a3 = dot2(vv.w, WhP[4 * c + 3], a3);
        }
        float acc = (a0 + a1) + (a2 + a3);
        acc += __shfl_xor(acc, 32);            // combine the two halves
        float cq = __cosf(acc + xpc);

        // inclusive prefix over q (stride-1 lanes within 8-group) — DPP
        float s = cq;
        { float u1 = dppf<DPP_SHR1>(s); if (q >= 1) s *= u1; }
        { float u2 = dppf<DPP_SHR2>(s); if (q >= 2) s *= u2; }
        { float u4 = dppf<DPP_SHR4>(s); if (q >= 4) s *= u4; }
        // product of c1..c7 via 3-stage butterfly — DPP
        float v = (q == 0) ? 1.0f : cq;
        v *= dppf<DPP_XOR1>(v);
        v *= dppf<DPP_XOR2>(v);
        v *= dppf<DPP_HMIR>(v);
        float outv = (q == 0) ? v : s;
        float onx  = dppf<DPP_SHL1>(outv);
        if (lw < 32 && !(lw & 1))
            ogS[w * 16 + (lw >> 1)] = pack2(outv, onx);
        // intra-wave LDS RAW -> compiler-inserted lgkmcnt wait, no barrier

        // ---- Phase B/C: qp dots + activations + LSTM cell (lane = h-dim) ----
        const uint4* ogp = (const uint4*)&ogS[w * 16];
        uint4 og0 = ogp[0], og1 = ogp[1], og2 = ogp[2], og3 = ogp[3];
        float d0 = dot2(og0.x, WqpP[0], bqp);
        d0 = dot2(og0.y, WqpP[1], d0);
        d0 = dot2(og0.z, WqpP[2], d0);
        d0 = dot2(og0.w, WqpP[3], d0);
        float d1 = dot2(og1.x, WqpP[0], bqp);
        d1 = dot2(og1.y, WqpP[1], d1);
        d1 = dot2(og1.z, WqpP[2], d1);
        d1 = dot2(og1.w, WqpP[3], d1);
        float d2 = dot2(og2.x, WqpP[0], bqp);
        d2 = dot2(og2.y, WqpP[1], d2);
        d2 = dot2(og2.z, WqpP[2], d2);
        d2 = dot2(og2.w, WqpP[3], d2);
        float d3 = dot2(og3.x, WqpP[0], bqp);
        d3 = dot2(og3.y, WqpP[1], d3);
        d3 = dot2(og3.z, WqpP[2], d3);
        d3 = dot2(og3.w, WqpP[3], d3);
        float fv = fast_sigmoid(d0);
        float iv = fast_sigmoid(d1);
        float gv = fast_tanh(d2);
        float ov = fast_sigmoid(d3);
        cx = fmaf(fv, cx, iv * gv);
        float hm = ov * fast_tanh(cx);
        float hmn = dppf<DPP_SHL1>(hm);
        if (!(tid & 1))
            hmS[(tid >> 5) * 20 + ((tid >> 1) & 15)] = pack2(hm, hmn);
        lds_barrier();                          // barrier 1

        // ---- Phase D: attn projection (redundant per wave; 8 lanes/output) ----
        const uint4* mp = (const uint4*)&hmS[q * 20];
        uint4 m0 = mp[0], m1 = mp[1], m2 = mp[2], m3 = mp[3];
        float s0 = dot2(m0.x, WapP[ 0], 0.f);
        s0 = dot2(m0.y, WapP[ 1], s0);
        s0 = dot2(m0.z, WapP[ 2], s0);
        s0 = dot2(m0.w, WapP[ 3], s0);
        float s1 = dot2(m1.x, WapP[ 4], 0.f);
        s1 = dot2(m1.y, WapP[ 5], s1);
        s1 = dot2(m1.z, WapP[ 6], s1);
        s1 = dot2(m1.w, WapP[ 7], s1);
        float s2 = dot2(m2.x, WapP[ 8], 0.f);
        s2 = dot2(m2.y, WapP[ 9], s2);
        s2 = dot2(m2.z, WapP[10], s2);
        s2 = dot2(m2.w, WapP[11], s2);
        float s3 = dot2(m3.x, WapP[12], 0.f);
        s3 = dot2(m3.y, WapP[13], s3);
        s3 = dot2(m3.z, WapP[14], s3);
        s3 = dot2(m3.w, WapP[15], s3);
        float sd = (s0 + s1) + (s2 + s3);
        sd += dppf<DPP_XOR1>(sd);
        sd += dppf<DPP_XOR2>(sd);
        sd += dppf<DPP_HMIR>(sd);
        float co = __cosf(sd + bap);
        if (!(lw & 7)) caS[w * 8 + o] = co;     // per-wave copy, same-wave read

        // ---- Phase E: hx = attn-qgate . W_attn_back + b (lane = h-dim) ----
        float4 cA = *(const float4*)&caS[w * 8];
        float4 cB = *(const float4*)&caS[w * 8 + 4];
        float p1 = cA.x * cA.y;
        float p2 = p1 * cA.z;
        float p3 = p2 * cA.w;
        float p4 = p3 * cB.x;
        float p5 = p4 * cB.y;
        float p6 = p5 * cB.z;
        float p7 = p6 * cB.w;
        float q12 = cA.y * cA.z, q34 = cA.w * cB.x, q56 = cB.y * cB.z;
        float p0 = (q12 * q34) * (q56 * cB.w);
        u32 oq0 = pack2(p0, p1);
        u32 oq1 = pack2(p2, p3);
        u32 oq2 = pack2(p4, p5);
        u32 oq3 = pack2(p6, p7);
        float hv = dot2(oq0, WabP[0], bab);
        hv = dot2(oq1, WabP[1], hv);
        hv = dot2(oq2, WabP[2], hv);
        hv = dot2(oq3, WabP[3], hv);
        hx = hv;
        out[((size_t)t * BATCH + b) * HDIM + tid] = hx;
        float hxn = dppf<DPP_SHL1>(hx);
        if (!(tid & 1))
            hS[tid >> 1] = pack2(hx, hxn);
        xpc = xpn;
        lds_barrier();                          // barrier 2
    }

    const size_t base = (size_t)T_STEPS * BATCH * HDIM;
    out[base + (size_t)b * HDIM + tid] = hx;
    out[base + (size_t)BATCH * HDIM + (size_t)b * HDIM + tid] = cx;
}

extern "C" void kernel_launch(void* const* d_in, const int* in_sizes, int n_in,
                              void* d_out, int out_size, void* d_ws, size_t ws_size,
                              hipStream_t stream) {
    const float* inputs      = (const float*)d_in[0];
    const float* W_proj      = (const float*)d_in[1];
    const float* b_proj      = (const float*)d_in[2];
    const float* theta_gate  = (const float*)d_in[3];
    const float* W_qproj     = (const float*)d_in[4];
    const float* b_qproj     = (const float*)d_in[5];
    const float* theta_attn  = (const float*)d_in[6];
    const float* W_attn_proj = (const float*)d_in[7];
    const float* b_attn_proj = (const float*)d_in[8];
    const float* W_attn_back = (const float*)d_in[9];
    const float* b_attn_back = (const float*)d_in[10];
    float* outp = (float*)d_out;
    float* xp   = (float*)d_ws;   // 256*512*32 f32 = 16.8 MB

    xproj_kernel<<<(T_STEPS * BATCH) / 64, 256, 0, stream>>>(
        inputs, W_proj, b_proj, theta_gate, xp);
    qlstm_main<<<BATCH, 256, 0, stream>>>(
        xp, W_proj, W_qproj, b_qproj, theta_attn,
        W_attn_proj, b_attn_proj, W_attn_back, b_attn_back, outp);
}